// Round 4
// baseline (373.107 us; speedup 1.0000x reference)
//
#include <hip/hip_runtime.h>
#include <stdint.h>

typedef unsigned short u16;
typedef __bf16 bf16x8 __attribute__((ext_vector_type(8)));
typedef float f32x4 __attribute__((ext_vector_type(4)));

// ---------- small helpers ----------
__device__ __forceinline__ u16 f2b(float f) {
  uint32_t u = __float_as_uint(f);
  u += 0x7FFFu + ((u >> 16) & 1u);   // RNE (inputs are finite/normal)
  return (u16)(u >> 16);
}
__device__ __forceinline__ float b2f(u16 u) {
  return __uint_as_float(((uint32_t)u) << 16);
}

// ---------- convert fp32 -> bf16, vectorized ----------
__global__ __launch_bounds__(256) void cvt_kernel(const float* __restrict__ s,
                                                  u16* __restrict__ d, int n4) {
  int i = blockIdx.x * 256 + threadIdx.x;
  if (i >= n4) return;
  float4 v = reinterpret_cast<const float4*>(s)[i];
  ushort4 o;
  o.x = f2b(v.x); o.y = f2b(v.y); o.z = f2b(v.z); o.w = f2b(v.w);
  reinterpret_cast<ushort4*>(d)[i] = o;
}

// ---------- transpose 1024x1024 fp32 -> bf16 [N][K] ----------
__global__ __launch_bounds__(256) void transpose_kernel(const float* __restrict__ s,
                                                        u16* __restrict__ d) {
  __shared__ float tile[32][33];
  const int tx = threadIdx.x, ty = threadIdx.y;          // (32, 8)
  const int bx = blockIdx.x * 32, by = blockIdx.y * 32;
#pragma unroll
  for (int j = 0; j < 32; j += 8)
    tile[ty + j][tx] = s[(size_t)(by + ty + j) * 1024 + bx + tx];
  __syncthreads();
#pragma unroll
  for (int j = 0; j < 32; j += 8)
    d[(size_t)(bx + ty + j) * 1024 + by + tx] = f2b(tile[tx][ty + j]);
}

// ---------- GEMM: C[M,N] = A[M,K=1024] * Bt[N,K=1024]^T, 128x128 tile, BK=32 ----------
// LDS layout: [row][k] as 128 rows x 32 bf16 (64B rows), XOR-swizzled 16B chunks:
//   phys_chunk(r,g) = g ^ ((r>>1)&3). Staged linearly via global_load_lds with
//   inverse-swizzled GLOBAL source (G21: both-sides-or-neither).
__device__ __forceinline__ void stage2(const u16* __restrict__ g, int row0, int k0,
                                       u16* lds, int t) {
#pragma unroll
  for (int j = 0; j < 2; ++j) {
    const int slot = j * 256 + t;                  // 16B slot index in 8KB tile
    const int r = slot >> 2;                       // tile row
    const int gl = (slot & 3) ^ ((r >> 1) & 3);    // logical k-chunk for this phys slot
    const u16* src = g + (((size_t)(row0 + r)) << 10) + (k0 + (gl << 3));
    u16* dst = lds + ((j * 256 + (t & 192)) << 3); // wave-uniform base; HW adds lane*16B
    __builtin_amdgcn_global_load_lds((const __attribute__((address_space(1))) void*)src,
                                     (__attribute__((address_space(3))) void*)dst,
                                     16, 0, 0);
  }
}

template <bool OUT_BF16>
__device__ __forceinline__ void gemm128(const u16* __restrict__ A, const u16* __restrict__ Bt,
                                        const float* __restrict__ bias, int m0, int n0,
                                        float scale, void* outp) {
  __shared__ alignas(16) u16 As[128 * 32];
  __shared__ alignas(16) u16 Bs[128 * 32];
  const int t = threadIdx.x;
  const int lane = t & 63, w = t >> 6;
  const int wr = (w >> 1) * 64, wc = (w & 1) * 64;   // wave 64x64 sub-tile
  const int lr = lane & 15, lg = lane >> 4;          // frag row-in-16, k-chunk

  f32x4 acc[4][4] = {};

  for (int k0 = 0; k0 < 1024; k0 += 32) {
    stage2(A, m0, k0, As, t);
    stage2(Bt, n0, k0, Bs, t);
    __syncthreads();

    bf16x8 af[4], bfr[4];
#pragma unroll
    for (int i = 0; i < 4; ++i) {
      const int r = wr + i * 16 + lr;
      af[i] = *reinterpret_cast<const bf16x8*>(&As[(r << 5) + (((lg ^ (r >> 1)) & 3) << 3)]);
    }
#pragma unroll
    for (int i = 0; i < 4; ++i) {
      const int r = wc + i * 16 + lr;
      bfr[i] = *reinterpret_cast<const bf16x8*>(&Bs[(r << 5) + (((lg ^ (r >> 1)) & 3) << 3)]);
    }
#pragma unroll
    for (int mi = 0; mi < 4; ++mi)
#pragma unroll
      for (int ni = 0; ni < 4; ++ni)
        acc[mi][ni] = __builtin_amdgcn_mfma_f32_16x16x32_bf16(af[mi], bfr[ni], acc[mi][ni], 0, 0, 0);
    __syncthreads();
  }

  // epilogue: C/D layout col=lane&15, row=(lane>>4)*4+reg (m89)
  const int cr = (lane >> 4) * 4, cc = lane & 15;
#pragma unroll
  for (int mi = 0; mi < 4; ++mi) {
#pragma unroll
    for (int ni = 0; ni < 4; ++ni) {
      const int gn = n0 + wc + ni * 16 + cc;
      const float bv = bias[gn];
#pragma unroll
      for (int i = 0; i < 4; ++i) {
        const int gm = m0 + wr + mi * 16 + cr + i;
        const float v = (acc[mi][ni][i] + bv) * scale;
        if (OUT_BF16)
          ((u16*)outp)[((size_t)gm << 10) + gn] = f2b(v);
        else
          ((float*)outp)[((size_t)gm << 10) + gn] = v;
      }
    }
  }
}

// fused QKV: grid (64, 24): y = seg*8 + ntile
__global__ __launch_bounds__(256) void gemm_qkv_kernel(
    const u16* __restrict__ XB, const u16* __restrict__ Wq, const u16* __restrict__ Wk,
    const u16* __restrict__ Wv, const float* __restrict__ bq, const float* __restrict__ bk,
    const float* __restrict__ bv, u16* __restrict__ Q, u16* __restrict__ K, u16* __restrict__ V) {
  const int seg = blockIdx.y >> 3, nt = blockIdx.y & 7;
  const u16* B = seg == 0 ? Wq : (seg == 1 ? Wk : Wv);
  const float* bias = seg == 0 ? bq : (seg == 1 ? bk : bv);
  u16* out = seg == 0 ? Q : (seg == 1 ? K : V);
  const float scale = seg == 0 ? 0.125f : 1.0f;   // 1/sqrt(C)=1/8, applied to (xW+b)
  gemm128<true>(XB, B, bias, blockIdx.x * 128, nt * 128, scale, out);
}

__global__ __launch_bounds__(256) void gemm_out_kernel(const u16* __restrict__ AB,
                                                       const u16* __restrict__ Wo,
                                                       const float* __restrict__ bo,
                                                       float* __restrict__ out) {
  gemm128<false>(AB, Wo, bo, blockIdx.x * 128, blockIdx.y * 128, 1.0f, out);
}

// ---------- per-token channel attention: one wave per (token, head), lane = q ----------
// Writes IN-PLACE over Q (each wave reads exactly the 64 elements it rewrites).
__global__ __launch_bounds__(256) void attn_kernel(u16* __restrict__ Qb,
                                                   const u16* __restrict__ Kb,
                                                   const u16* __restrict__ Vb) {
  const int w = threadIdx.x >> 6, lane = threadIdx.x & 63;
  const int wid = blockIdx.x * 4 + w;                      // token*16 + head
  const size_t base = (size_t)(wid >> 4) * 1024 + (size_t)(wid & 15) * 64;
  const float q  = b2f(Qb[base + lane]);   // already scaled by 1/8
  const float kv = b2f(Kb[base + lane]);
  const float vv = b2f(Vb[base + lane]);

  // row max over k<=lane of q*K[k] via prefix max/min of K (6 shuffle steps)
  float pmax = kv, pmin = kv;
#pragma unroll
  for (int d = 1; d < 64; d <<= 1) {
    float a = __shfl_up(pmax, d);
    float b = __shfl_up(pmin, d);
    if (lane >= d) { pmax = fmaxf(pmax, a); pmin = fminf(pmin, b); }
  }
  const float m = (q >= 0.f) ? q * pmax : q * pmin;

  float denom = 0.f, acc = 0.f;
#pragma unroll
  for (int k = 0; k < 64; ++k) {
    const float Kk = __shfl(kv, k);
    const float Vk = __shfl(vv, k);
    const float e = (k <= lane) ? __expf(fmaf(q, Kk, -m)) : 0.f;
    denom += e;
    acc = fmaf(e, Vk, acc);
  }
  Qb[base + lane] = f2b(acc / denom);
}

// ---------- launch ----------
extern "C" void kernel_launch(void* const* d_in, const int* in_sizes, int n_in,
                              void* d_out, int out_size, void* d_ws, size_t ws_size,
                              hipStream_t stream) {
  const float* x  = (const float*)d_in[0];
  const float* Wq = (const float*)d_in[1];
  const float* bq = (const float*)d_in[2];
  const float* Wk = (const float*)d_in[3];
  const float* bk = (const float*)d_in[4];
  const float* Wv = (const float*)d_in[5];
  const float* bv = (const float*)d_in[6];
  const float* Wo = (const float*)d_in[7];
  const float* bo = (const float*)d_in[8];
  float* out = (float*)d_out;

  char* ws = (char*)d_ws;
  u16* XB  = (u16*)(ws);                          // x bf16            16 MB
  u16* WqB = (u16*)(ws + (16ull << 20));          // Wq^T bf16          2 MB
  u16* WkB = (u16*)(ws + (18ull << 20));
  u16* WvB = (u16*)(ws + (20ull << 20));
  u16* WoB = (u16*)(ws + (22ull << 20));
  u16* Qb  = (u16*)(ws + (24ull << 20));          // Q bf16 (attn out in-place) 16 MB
  u16* Kb  = (u16*)(ws + (40ull << 20));
  u16* Vb  = (u16*)(ws + (56ull << 20));          // total 72 MB

  cvt_kernel<<<8192, 256, 0, stream>>>(x, XB, 2097152);   // 8.39M elems / 4
  dim3 tb(32, 8), tg(32, 32);
  transpose_kernel<<<tg, tb, 0, stream>>>(Wq, WqB);
  transpose_kernel<<<tg, tb, 0, stream>>>(Wk, WkB);
  transpose_kernel<<<tg, tb, 0, stream>>>(Wv, WvB);
  transpose_kernel<<<tg, tb, 0, stream>>>(Wo, WoB);

  gemm_qkv_kernel<<<dim3(64, 24), 256, 0, stream>>>(XB, WqB, WkB, WvB, bq, bk, bv, Qb, Kb, Vb);
  attn_kernel<<<32768, 256, 0, stream>>>(Qb, Kb, Vb);
  gemm_out_kernel<<<dim3(64, 8), 256, 0, stream>>>(Qb, WoB, bo, out);
}

// Round 5
// 308.603 us; speedup vs baseline: 1.2090x; 1.2090x over previous
//
#include <hip/hip_runtime.h>
#include <stdint.h>

typedef unsigned short u16;
typedef unsigned int u32;
typedef __bf16 bf16x8 __attribute__((ext_vector_type(8)));
typedef float f32x4 __attribute__((ext_vector_type(4)));

// ---------- small helpers ----------
__device__ __forceinline__ u16 f2b(float f) {
  uint32_t u = __float_as_uint(f);
  u += 0x7FFFu + ((u >> 16) & 1u);   // RNE (inputs are finite/normal)
  return (u16)(u >> 16);
}
__device__ __forceinline__ float b2f(u16 u) {
  return __uint_as_float(((uint32_t)u) << 16);
}
__device__ __forceinline__ float b2f_lo(u32 w) {  // low bf16 of a dword
  return __uint_as_float(w << 16);
}
__device__ __forceinline__ float b2f_hi(u32 w) {  // high bf16 of a dword
  return __uint_as_float(w & 0xffff0000u);
}

// ---------- convert fp32 -> bf16, vectorized ----------
__global__ __launch_bounds__(256) void cvt_kernel(const float* __restrict__ s,
                                                  u16* __restrict__ d, int n4) {
  int i = blockIdx.x * 256 + threadIdx.x;
  if (i >= n4) return;
  float4 v = reinterpret_cast<const float4*>(s)[i];
  ushort4 o;
  o.x = f2b(v.x); o.y = f2b(v.y); o.z = f2b(v.z); o.w = f2b(v.w);
  reinterpret_cast<ushort4*>(d)[i] = o;
}

// ---------- transpose 1024x1024 fp32 -> bf16 [N][K] ----------
__global__ __launch_bounds__(256) void transpose_kernel(const float* __restrict__ s,
                                                        u16* __restrict__ d) {
  __shared__ float tile[32][33];
  const int tx = threadIdx.x, ty = threadIdx.y;          // (32, 8)
  const int bx = blockIdx.x * 32, by = blockIdx.y * 32;
#pragma unroll
  for (int j = 0; j < 32; j += 8)
    tile[ty + j][tx] = s[(size_t)(by + ty + j) * 1024 + bx + tx];
  __syncthreads();
#pragma unroll
  for (int j = 0; j < 32; j += 8)
    d[(size_t)(bx + ty + j) * 1024 + by + tx] = f2b(tile[tx][ty + j]);
}

// ---------- GEMM: C[M,N] = A[M,K=1024] * Bt[N,K=1024]^T, 128x128 tile, BK=32 ----------
// LDS layout: [row][k] as 128 rows x 32 bf16 (64B rows), XOR-swizzled 16B chunks:
//   phys_chunk(r,g) = g ^ ((r>>1)&3). Staged linearly via global_load_lds with
//   inverse-swizzled GLOBAL source (G21: both-sides-or-neither).
__device__ __forceinline__ void stage2(const u16* __restrict__ g, int row0, int k0,
                                       u16* lds, int t) {
#pragma unroll
  for (int j = 0; j < 2; ++j) {
    const int slot = j * 256 + t;                  // 16B slot index in 8KB tile
    const int r = slot >> 2;                       // tile row
    const int gl = (slot & 3) ^ ((r >> 1) & 3);    // logical k-chunk for this phys slot
    const u16* src = g + (((size_t)(row0 + r)) << 10) + (k0 + (gl << 3));
    u16* dst = lds + ((j * 256 + (t & 192)) << 3); // wave-uniform base; HW adds lane*16B
    __builtin_amdgcn_global_load_lds((const __attribute__((address_space(1))) void*)src,
                                     (__attribute__((address_space(3))) void*)dst,
                                     16, 0, 0);
  }
}

template <bool OUT_BF16>
__device__ __forceinline__ void gemm128(const u16* __restrict__ A, const u16* __restrict__ Bt,
                                        const float* __restrict__ bias, int m0, int n0,
                                        float scale, void* outp) {
  __shared__ alignas(16) u16 As[128 * 32];
  __shared__ alignas(16) u16 Bs[128 * 32];
  const int t = threadIdx.x;
  const int lane = t & 63, w = t >> 6;
  const int wr = (w >> 1) * 64, wc = (w & 1) * 64;   // wave 64x64 sub-tile
  const int lr = lane & 15, lg = lane >> 4;          // frag row-in-16, k-chunk

  f32x4 acc[4][4] = {};

  for (int k0 = 0; k0 < 1024; k0 += 32) {
    stage2(A, m0, k0, As, t);
    stage2(Bt, n0, k0, Bs, t);
    __syncthreads();

    bf16x8 af[4], bfr[4];
#pragma unroll
    for (int i = 0; i < 4; ++i) {
      const int r = wr + i * 16 + lr;
      af[i] = *reinterpret_cast<const bf16x8*>(&As[(r << 5) + (((lg ^ (r >> 1)) & 3) << 3)]);
    }
#pragma unroll
    for (int i = 0; i < 4; ++i) {
      const int r = wc + i * 16 + lr;
      bfr[i] = *reinterpret_cast<const bf16x8*>(&Bs[(r << 5) + (((lg ^ (r >> 1)) & 3) << 3)]);
    }
#pragma unroll
    for (int mi = 0; mi < 4; ++mi)
#pragma unroll
      for (int ni = 0; ni < 4; ++ni)
        acc[mi][ni] = __builtin_amdgcn_mfma_f32_16x16x32_bf16(af[mi], bfr[ni], acc[mi][ni], 0, 0, 0);
    __syncthreads();
  }

  // epilogue: C/D layout col=lane&15, row=(lane>>4)*4+reg (m89)
  const int cr = (lane >> 4) * 4, cc = lane & 15;
#pragma unroll
  for (int mi = 0; mi < 4; ++mi) {
#pragma unroll
    for (int ni = 0; ni < 4; ++ni) {
      const int gn = n0 + wc + ni * 16 + cc;
      const float bv = bias[gn];
#pragma unroll
      for (int i = 0; i < 4; ++i) {
        const int gm = m0 + wr + mi * 16 + cr + i;
        const float v = (acc[mi][ni][i] + bv) * scale;
        if (OUT_BF16)
          ((u16*)outp)[((size_t)gm << 10) + gn] = f2b(v);
        else
          ((float*)outp)[((size_t)gm << 10) + gn] = v;
      }
    }
  }
}

// fused QKV: grid (64, 24): y = seg*8 + ntile
__global__ __launch_bounds__(256) void gemm_qkv_kernel(
    const u16* __restrict__ XB, const u16* __restrict__ Wq, const u16* __restrict__ Wk,
    const u16* __restrict__ Wv, const float* __restrict__ bq, const float* __restrict__ bk,
    const float* __restrict__ bv, u16* __restrict__ Q, u16* __restrict__ K, u16* __restrict__ V) {
  const int seg = blockIdx.y >> 3, nt = blockIdx.y & 7;
  const u16* B = seg == 0 ? Wq : (seg == 1 ? Wk : Wv);
  const float* bias = seg == 0 ? bq : (seg == 1 ? bk : bv);
  u16* out = seg == 0 ? Q : (seg == 1 ? K : V);
  const float scale = seg == 0 ? 0.125f : 1.0f;   // 1/sqrt(C)=1/8, applied to (xW+b)
  gemm128<true>(XB, B, bias, blockIdx.x * 128, nt * 128, scale, out);
}

__global__ __launch_bounds__(256) void gemm_out_kernel(const u16* __restrict__ AB,
                                                       const u16* __restrict__ Wo,
                                                       const float* __restrict__ bo,
                                                       float* __restrict__ out) {
  gemm128<false>(AB, Wo, bo, blockIdx.x * 128, blockIdx.y * 128, 1.0f, out);
}

// ---------- per-token channel attention: one wave per (token, head), lane = q ----------
// v2: no shuffles at all. Each lane loads the full 64-elem K and V vectors
// (same addresses across lanes -> L2 broadcast; data is L2-hot from the QKV GEMM).
// Max-subtraction dropped: scores = Q[q]*K[k] with |score| << 1 (softmax is
// shift-invariant; no overflow possible), so softmax = exp(s)/sum(exp(s)).
// Writes IN-PLACE over Q (each wave reads exactly the 64 elements it rewrites).
__global__ __launch_bounds__(256) void attn_kernel(u16* __restrict__ Qb,
                                                   const u16* __restrict__ Kb,
                                                   const u16* __restrict__ Vb) {
  const int w = threadIdx.x >> 6, lane = threadIdx.x & 63;
  const int wid = blockIdx.x * 4 + w;                      // token*16 + head
  const size_t base = (size_t)(wid >> 4) * 1024 + (size_t)(wid & 15) * 64;

  const float q = b2f(Qb[base + lane]);                    // already scaled by 1/sqrt(C)
#if __has_builtin(__builtin_amdgcn_exp2f)
  const float qs = q * 1.44269504088896340736f;            // fold ln2 into q: exp(qx)=2^(qs*x)
#define ATTN_EXP(KV) __builtin_amdgcn_exp2f(qs * (KV))
#else
#define ATTN_EXP(KV) __expf(q * (KV))
#endif

  const uint4* K4 = reinterpret_cast<const uint4*>(Kb + base);  // 128B-aligned
  const uint4* V4 = reinterpret_cast<const uint4*>(Vb + base);

  // dual accumulator chains (even/odd) to expose packed-f32 / ILP
  float d0 = 0.f, d1 = 0.f, a0 = 0.f, a1 = 0.f;
#pragma unroll
  for (int c = 0; c < 8; ++c) {
    const uint4 kc = K4[c];
    const uint4 vc = V4[c];
    const u32* kw = reinterpret_cast<const u32*>(&kc);
    const u32* vw = reinterpret_cast<const u32*>(&vc);
#pragma unroll
    for (int j = 0; j < 4; ++j) {
      const int k0 = c * 8 + j * 2;
      const float Ka = b2f_lo(kw[j]), Kb_ = b2f_hi(kw[j]);
      const float Va = b2f_lo(vw[j]), Vb_ = b2f_hi(vw[j]);
      const float ea = (k0     <= lane) ? ATTN_EXP(Ka) : 0.f;  // causal mask k<=q
      const float eb = (k0 + 1 <= lane) ? ATTN_EXP(Kb_) : 0.f;
      d0 += ea; a0 = fmaf(ea, Va, a0);
      d1 += eb; a1 = fmaf(eb, Vb_, a1);
    }
  }
  Qb[base + lane] = f2b((a0 + a1) / (d0 + d1));
#undef ATTN_EXP
}

// ---------- launch ----------
extern "C" void kernel_launch(void* const* d_in, const int* in_sizes, int n_in,
                              void* d_out, int out_size, void* d_ws, size_t ws_size,
                              hipStream_t stream) {
  const float* x  = (const float*)d_in[0];
  const float* Wq = (const float*)d_in[1];
  const float* bq = (const float*)d_in[2];
  const float* Wk = (const float*)d_in[3];
  const float* bk = (const float*)d_in[4];
  const float* Wv = (const float*)d_in[5];
  const float* bv = (const float*)d_in[6];
  const float* Wo = (const float*)d_in[7];
  const float* bo = (const float*)d_in[8];
  float* out = (float*)d_out;

  char* ws = (char*)d_ws;
  u16* XB  = (u16*)(ws);                          // x bf16            16 MB
  u16* WqB = (u16*)(ws + (16ull << 20));          // Wq^T bf16          2 MB
  u16* WkB = (u16*)(ws + (18ull << 20));
  u16* WvB = (u16*)(ws + (20ull << 20));
  u16* WoB = (u16*)(ws + (22ull << 20));
  u16* Qb  = (u16*)(ws + (24ull << 20));          // Q bf16 (attn out in-place) 16 MB
  u16* Kb  = (u16*)(ws + (40ull << 20));
  u16* Vb  = (u16*)(ws + (56ull << 20));          // total 72 MB

  cvt_kernel<<<8192, 256, 0, stream>>>(x, XB, 2097152);   // 8.39M elems / 4
  dim3 tb(32, 8), tg(32, 32);
  transpose_kernel<<<tg, tb, 0, stream>>>(Wq, WqB);
  transpose_kernel<<<tg, tb, 0, stream>>>(Wk, WkB);
  transpose_kernel<<<tg, tb, 0, stream>>>(Wv, WvB);
  transpose_kernel<<<tg, tb, 0, stream>>>(Wo, WoB);

  gemm_qkv_kernel<<<dim3(64, 24), 256, 0, stream>>>(XB, WqB, WkB, WvB, bq, bk, bv, Qb, Kb, Vb);
  attn_kernel<<<32768, 256, 0, stream>>>(Qb, Kb, Vb);
  gemm_out_kernel<<<dim3(64, 8), 256, 0, stream>>>(Qb, WoB, bo, out);
}